// Round 1
// 634.068 us; speedup vs baseline: 1.0689x; 1.0689x over previous
//
#include <hip/hip_runtime.h>
#include <hip/hip_bf16.h>
#include <stdint.h>

typedef __bf16 bf16_t;
typedef __bf16 bf16x8 __attribute__((ext_vector_type(8)));
typedef __bf16 bf16x4 __attribute__((ext_vector_type(4)));
typedef float  v4f    __attribute__((ext_vector_type(4)));
typedef float  f32x4  __attribute__((ext_vector_type(4)));

#define GLDS16(gp, lp)                                                         \
  __builtin_amdgcn_global_load_lds(                                            \
      (__attribute__((address_space(1))) void*)(gp),                           \
      (__attribute__((address_space(3))) void*)(lp), 16, 0, 0)

#define BATCH 2048
#define KEXP  64
#define NOUT  512
#define R1    1024

// ---------------------------------------------------------------- cast u -> bf16
__global__ __launch_bounds__(256) void cast_u_k(const float* __restrict__ u,
                                                bf16_t* __restrict__ ub) {
  int idx = blockIdx.x * 256 + threadIdx.x;          // float4 index
  float4 v = ((const float4*)u)[idx];
  bf16x4 o;
  o.x = (bf16_t)v.x; o.y = (bf16_t)v.y; o.z = (bf16_t)v.z; o.w = (bf16_t)v.w;
  ((bf16x4*)ub)[idx] = o;
}

// ------------------------------------------- cast W_con|W_recon -> combined bf16
// wb layout: [k][n(0..1023)][i], n<512 from W_con, n>=512 from W_recon.
__global__ __launch_bounds__(256) void cast_w_k(const float* __restrict__ wcon,
                                                const float* __restrict__ wrec,
                                                bf16_t* __restrict__ wb) {
  const size_t tid = (size_t)blockIdx.x * 256 + threadIdx.x;
#pragma unroll
  for (int it = 0; it < 8; ++it) {
    size_t idx = tid + (size_t)it * (8192u * 256u);   // float4 index
    size_t e = idx << 2;
    int k = (int)(e >> 20);
    int n = (int)((e >> 10) & 1023);
    int i = (int)(e & 1023);
    const float* src = (n < NOUT)
        ? (wcon + (((size_t)k * NOUT + n) << 10) + i)
        : (wrec + (((size_t)k * NOUT + (n - NOUT)) << 10) + i);
    f32x4 v = __builtin_nontemporal_load((const f32x4*)src);
    bf16x4 o;
    o.x = (bf16_t)v.x; o.y = (bf16_t)v.y; o.z = (bf16_t)v.z; o.w = (bf16_t)v.w;
    ((bf16x4*)wb)[idx] = o;
  }
}

// ------------------------------------------------------------- d2 (fp32 GEMM)
__global__ __launch_bounds__(256) void psi_d2_k(const float* __restrict__ z,
                                                const float* __restrict__ mu,
                                                const float* __restrict__ sig,
                                                float* __restrict__ d2g) {
  __shared__ float dv[64][132];   // +4 pad
  __shared__ float Ss[16][128];   // one 16-row chunk of S_k
  const int t = threadIdx.x;
  const int k = blockIdx.x;
  const int b0 = blockIdx.y * 64;

  const float* muk = mu + k * 128;
#pragma unroll
  for (int i = 0; i < 8; ++i) {
    int f4 = i * 256 + t;                 // float4 index within 64x128 tile
    int row = f4 >> 5, c4 = f4 & 31;
    float4 zq = ((const float4*)(z + (size_t)(b0 + row) * 128))[c4];
    float4 mq = ((const float4*)muk)[c4];
    float4 dq;
    dq.x = mq.x - zq.x; dq.y = mq.y - zq.y;
    dq.z = mq.z - zq.z; dq.w = mq.w - zq.w;
    *(float4*)&dv[row][c4 * 4] = dq;
  }

  const int et = t & 15, bt = t >> 4;     // e-thread, b-thread
  const float* Sk = sig + ((size_t)k << 14);
  float acc[4][8];
#pragma unroll
  for (int j = 0; j < 4; ++j)
#pragma unroll
    for (int i = 0; i < 8; ++i) acc[j][i] = 0.f;

  for (int dblk = 0; dblk < 8; ++dblk) {
    __syncthreads();
#pragma unroll
    for (int i = 0; i < 2; ++i) {
      int f4 = i * 256 + t;               // 0..511 within 16x128 chunk
      int row = f4 >> 5, c4 = f4 & 31;
      *(float4*)&Ss[row][c4 * 4] =
          ((const float4*)(Sk + (size_t)(dblk * 16 + row) * 128))[c4];
    }
    __syncthreads();

#pragma unroll
    for (int d4 = 0; d4 < 4; ++d4) {
      float4 a[4];
#pragma unroll
      for (int j = 0; j < 4; ++j)
        a[j] = *(const float4*)&dv[bt * 4 + j][dblk * 16 + d4 * 4];
#pragma unroll
      for (int dd = 0; dd < 4; ++dd) {
        float4 s0 = *(const float4*)&Ss[d4 * 4 + dd][et * 8];
        float4 s1 = *(const float4*)&Ss[d4 * 4 + dd][et * 8 + 4];
        float av[4] = {a[0][dd], a[1][dd], a[2][dd], a[3][dd]};
#pragma unroll
        for (int j = 0; j < 4; ++j) {
          acc[j][0] = fmaf(s0.x, av[j], acc[j][0]);
          acc[j][1] = fmaf(s0.y, av[j], acc[j][1]);
          acc[j][2] = fmaf(s0.z, av[j], acc[j][2]);
          acc[j][3] = fmaf(s0.w, av[j], acc[j][3]);
          acc[j][4] = fmaf(s1.x, av[j], acc[j][4]);
          acc[j][5] = fmaf(s1.y, av[j], acc[j][5]);
          acc[j][6] = fmaf(s1.z, av[j], acc[j][6]);
          acc[j][7] = fmaf(s1.w, av[j], acc[j][7]);
        }
      }
    }
  }

  float v2[4];
#pragma unroll
  for (int j = 0; j < 4; ++j) {
    float s = 0.f;
#pragma unroll
    for (int i = 0; i < 8; ++i) s = fmaf(acc[j][i], acc[j][i], s);
    v2[j] = s;
  }
#pragma unroll
  for (int j = 0; j < 4; ++j) {
    v2[j] += __shfl_xor(v2[j], 1);
    v2[j] += __shfl_xor(v2[j], 2);
    v2[j] += __shfl_xor(v2[j], 4);
    v2[j] += __shfl_xor(v2[j], 8);
  }
  if (et == 0) {
#pragma unroll
    for (int j = 0; j < 4; ++j)
      d2g[(size_t)(b0 + bt * 4 + j) * 64 + k] = v2[j];
  }
}

// ----------------------------------------------------------- softmax over k
__global__ __launch_bounds__(256) void psi_sm_k(const float* __restrict__ d2g,
                                                float* __restrict__ psi) {
  const int b = blockIdx.x * 4 + (threadIdx.x >> 6);
  const int lane = threadIdx.x & 63;
  float x = fmaxf(d2g[(size_t)b * 64 + lane], 0.0f);  // MIN_CLAMP
  float m = x;
  m = fminf(m, __shfl_xor(m, 1));  m = fminf(m, __shfl_xor(m, 2));
  m = fminf(m, __shfl_xor(m, 4));  m = fminf(m, __shfl_xor(m, 8));
  m = fminf(m, __shfl_xor(m, 16)); m = fminf(m, __shfl_xor(m, 32));
  float ex = __expf(m - x);
  float s = ex;
  s += __shfl_xor(s, 1);  s += __shfl_xor(s, 2);  s += __shfl_xor(s, 4);
  s += __shfl_xor(s, 8);  s += __shfl_xor(s, 16); s += __shfl_xor(s, 32);
  psi[(size_t)b * 64 + lane] = ex / s;
}

// ------------------------------------------------------- fused bf16 MFMA GEMM
// grid (16 m-tiles, 8 n-tiles, 4 expert-chunks), 256 thr, 128x128 tile, BK=64.
// v5: T3+T4 pipeline. Double-buffered LDS, flattened K-loop of 256 steps
// (16 experts x 16 k-tiles), depth-2 prefetch with counted vmcnt(8) (never
// drained to 0 in the loop), raw s_barriers (no __syncthreads -> no
// compiler-forced vmcnt(0) drain), 2 phases/K-step with setprio(1) around
// each 16-MFMA cluster. Fragment math + XOR swizzle identical to v4
// (SQ_LDS_BANK_CONFLICT == 0 verified).
__global__ __launch_bounds__(256, 2)
void fused_gemm(const bf16_t* __restrict__ ub,   // [2048][1024]
                const bf16_t* __restrict__ wb,   // [64][1024][1024]
                const float* __restrict__ psi,   // [2048][64]
                const float* __restrict__ member,// [2048][64]
                float* __restrict__ out) {       // y[2048*512] ++ x[2048*512]
  __shared__ bf16_t Alds[2][128 * 64];   // 32 KiB
  __shared__ bf16_t Blds[2][128 * 64];   // 32 KiB
  __shared__ float  wlds[16][128];       // 8 KiB  (expert-major: conflict-free)

  const int t = threadIdx.x, lane = t & 63, wv = t >> 6;
  const int bm0 = blockIdx.x * 128;
  const int n0  = blockIdx.y * 128;
  const int e0  = blockIdx.z * 16;
  const bool is_y = (n0 < NOUT);
  const float* wsel = is_y ? psi : member;
  const int wm = wv & 1, wn = wv >> 1;
  const int l15 = lane & 15, quad = lane >> 4;
  const int fsw = l15 & 7;

  v4f acc[4][4], oacc[4][4];
#pragma unroll
  for (int mi = 0; mi < 4; ++mi)
#pragma unroll
    for (int ni = 0; ni < 4; ++ni)
#pragma unroll
      for (int r = 0; r < 4; ++r) { acc[mi][ni][r] = 0.f; oacc[mi][ni][r] = 0.f; }

  const int rA = wv * 8 + (lane >> 3);             // staging row in 32-row group
  const int c8 = (((lane & 7) ^ (lane >> 3)) * 8); // swizzled source column
  const bf16_t* au  = ub + (size_t)(bm0 + rA) * R1 + c8;
  const bf16_t* bw0 = wb + (size_t)(n0 + rA) * R1 + c8;

  const int aoff = (wm * 64 + l15) * 64;           // per-wave fragment bases
  const int boff = (wn * 64 + l15) * 64;
  const int co0 = (quad ^ fsw) * 8;                // ks=0 swizzled chunk
  const int co1 = ((4 + quad) ^ fsw) * 8;          // ks=1 swizzled chunk

  // stage global K-step s2 into buffer p (8 GLDS16 per thread: 4 A + 4 B)
  auto STAGE = [&](int s2, int p) {
    const int ex2 = e0 + (s2 >> 4);
    const int kk2 = (s2 & 15) << 6;
    const bf16_t* a = au + kk2;
    const bf16_t* b = bw0 + ((size_t)ex2 << 20) + kk2;
    bf16_t* Ad = &Alds[p][wv * 8 * 64];
    bf16_t* Bd = &Blds[p][wv * 8 * 64];
#pragma unroll
    for (int j = 0; j < 4; ++j)
      GLDS16(a + (size_t)(j * 32) * R1, Ad + j * 32 * 64);
#pragma unroll
    for (int j = 0; j < 4; ++j)
      GLDS16(b + (size_t)(j * 32) * R1, Bd + j * 32 * 64);
  };

  // ---- prologue: weight table + first two K-steps in flight
  {
    const int r = t >> 1, h = (t & 1) * 8;
    const float* src = wsel + (size_t)(bm0 + r) * 64 + e0 + h;
    f32x4 v0 = *(const f32x4*)src;
    f32x4 v1 = *(const f32x4*)(src + 4);
#pragma unroll
    for (int j = 0; j < 4; ++j) { wlds[h + j][r] = v0[j]; wlds[h + 4 + j][r] = v1[j]; }
  }
  STAGE(0, 0);
  STAGE(1, 1);
  asm volatile("s_waitcnt vmcnt(8) lgkmcnt(0)" ::: "memory");  // step-0 landed
  __builtin_amdgcn_s_barrier();

  for (int ke = 0; ke < 16; ++ke) {
#pragma unroll 2
    for (int kt = 0; kt < 16; ++kt) {
      const int p = kt & 1;                 // == s & 1
      const int s = (ke << 4) + kt;
      const bf16_t* Ap = &Alds[p][aoff];
      const bf16_t* Bp = &Blds[p][boff];

      // ---- phase 0 (ks = 0)
      bf16x8 a0[4], b0[4];
#pragma unroll
      for (int i = 0; i < 4; ++i) {
        a0[i] = *(const bf16x8*)(Ap + i * 16 * 64 + co0);
        b0[i] = *(const bf16x8*)(Bp + i * 16 * 64 + co0);
      }
      asm volatile("s_waitcnt lgkmcnt(0)" ::: "memory");
      __builtin_amdgcn_sched_barrier(0);
      __builtin_amdgcn_s_setprio(1);
#pragma unroll
      for (int mi = 0; mi < 4; ++mi)
#pragma unroll
        for (int ni = 0; ni < 4; ++ni)
          acc[mi][ni] = __builtin_amdgcn_mfma_f32_16x16x32_bf16(
              a0[mi], b0[ni], acc[mi][ni], 0, 0, 0);
      __builtin_amdgcn_s_setprio(0);

      // ---- phase 1 (ks = 1)
      bf16x8 a1[4], b1[4];
#pragma unroll
      for (int i = 0; i < 4; ++i) {
        a1[i] = *(const bf16x8*)(Ap + i * 16 * 64 + co1);
        b1[i] = *(const bf16x8*)(Bp + i * 16 * 64 + co1);
      }
      asm volatile("s_waitcnt lgkmcnt(0)" ::: "memory");
      __builtin_amdgcn_sched_barrier(0);
      __builtin_amdgcn_s_barrier();         // B1: all waves done reading buf p

      int s2 = s + 2; s2 = (s2 > 255) ? 255 : s2;  // clamped dup-stage at tail
      STAGE(s2, p);                          // overwrite buf p with step s+2

      __builtin_amdgcn_s_setprio(1);
#pragma unroll
      for (int mi = 0; mi < 4; ++mi)
#pragma unroll
        for (int ni = 0; ni < 4; ++ni)
          acc[mi][ni] = __builtin_amdgcn_mfma_f32_16x16x32_bf16(
              a1[mi], b1[ni], acc[mi][ni], 0, 0, 0);
      __builtin_amdgcn_s_setprio(0);

      asm volatile("s_waitcnt vmcnt(8)" ::: "memory");  // drain step s+1 only
      __builtin_amdgcn_s_barrier();         // B2: buf p^1 globally ready
    }

    // per-expert epilogue: oacc += |acc| * w[b, e0+ke]; reset acc
#pragma unroll
    for (int mi = 0; mi < 4; ++mi) {
      float wr[4];
#pragma unroll
      for (int r = 0; r < 4; ++r)
        wr[r] = wlds[ke][wm * 64 + mi * 16 + quad * 4 + r];
#pragma unroll
      for (int ni = 0; ni < 4; ++ni)
#pragma unroll
        for (int r = 0; r < 4; ++r) {
          oacc[mi][ni][r] += fabsf(acc[mi][ni][r]) * wr[r];
          acc[mi][ni][r] = 0.f;
        }
    }
  }

  float* obase = is_y ? out : out + (size_t)BATCH * NOUT;
  const int oc = (is_y ? n0 : n0 - NOUT) + wn * 64 + l15;
#pragma unroll
  for (int mi = 0; mi < 4; ++mi)
#pragma unroll
    for (int ni = 0; ni < 4; ++ni)
#pragma unroll
      for (int r = 0; r < 4; ++r) {
        int brow = bm0 + wm * 64 + mi * 16 + quad * 4 + r;
        atomicAdd(&obase[(size_t)brow * NOUT + oc + ni * 16], oacc[mi][ni][r]);
      }
  asm volatile("s_waitcnt vmcnt(0)" ::: "memory");  // drain dup-stages + atomics
}

extern "C" void kernel_launch(void* const* d_in, const int* in_sizes, int n_in,
                              void* d_out, int out_size, void* d_ws, size_t ws_size,
                              hipStream_t stream) {
  const float* z    = (const float*)d_in[0];
  const float* u    = (const float*)d_in[1];
  const float* mem  = (const float*)d_in[2];
  const float* mu   = (const float*)d_in[3];
  const float* sig  = (const float*)d_in[4];
  const float* wcon = (const float*)d_in[5];
  const float* wrec = (const float*)d_in[6];
  float* out = (float*)d_out;

  char* ws = (char*)d_ws;
  bf16_t* ub  = (bf16_t*)ws;                              // 4 MiB
  bf16_t* wb  = (bf16_t*)(ws + ((size_t)4 << 20));        // 128 MiB
  float*  psw = (float*)(ws + ((size_t)132 << 20));       // 512 KiB
  float*  d2g = (float*)(ws + ((size_t)132 << 20) + ((size_t)512 << 10));

  hipMemsetAsync(d_out, 0, (size_t)out_size * sizeof(float), stream);
  cast_u_k<<<2048, 256, 0, stream>>>(u, ub);
  cast_w_k<<<8192, 256, 0, stream>>>(wcon, wrec, wb);
  psi_d2_k<<<dim3(64, 32), 256, 0, stream>>>(z, mu, sig, d2g);
  psi_sm_k<<<512, 256, 0, stream>>>(d2g, psw);
  fused_gemm<<<dim3(16, 8, 4), 256, 0, stream>>>(ub, wb, psw, mem, out);
}